// Round 11
// baseline (171.924 us; speedup 1.0000x reference)
//
#include <hip/hip_runtime.h>

// ProxemicsFieldGenerator: 2-layer GAT on dense graph.
// b=16, n=1024, f0=32, h0=4, f1=16, FH=64, f2=32, h1=1.
// Single persistent kernel, 1024 blocks x 256 thr. Dependencies are per-batch,
// so phase boundaries are 16 INDEPENDENT per-batch barriers (64 blocks each,
// padded counters). All blocks work in every phase (16 rows/block in proj
// phases, shfl-reduced dots). PV on fp16 MFMA with V split hi+lo (R6-proven).
// [R11 = R10 resubmitted unchanged: R10 bench was a GPU-acquisition timeout.]

namespace {
constexpr int Nn  = 1024;
constexpr int F0  = 32;
constexpr int F1n = 16;
constexpr int FH  = 64;   // h0 * f1
constexpr int F2n = 32;
constexpr float LOG2E = 1.4426950408889634f;
constexpr float EPS   = 1e-5f;
constexpr float ALPHA = 0.2f;
}

typedef __attribute__((ext_vector_type(8))) _Float16 half8;
typedef __attribute__((ext_vector_type(4))) float f32x4;

union alignas(16) Smem {
  struct { float sum[8][33], ssq[8][33], mean[32], rstd[32], wt[2048], as[64], ad[64], x[16][33]; } p1;
  struct { float dst[Nn], red[4], ps[4][16]; } p2;
  struct { float mean[64], rstd[64], wt[2048], as[32], ad[32], x[16][65]; } p3;
  struct { float dst[Nn], red[4], comb[3][64][9], ps[16]; } p4;
};

// ---------------------------------------------------------------------------
// per-batch grid barrier: 64 blocks on a private padded counter.
// ---------------------------------------------------------------------------
__device__ __forceinline__ void batch_barrier(unsigned* c) {
  __syncthreads();
  if (threadIdx.x == 0) {
    __threadfence();   // release
    __hip_atomic_fetch_add(c, 1u, __ATOMIC_RELAXED, __HIP_MEMORY_SCOPE_AGENT);
    while (__hip_atomic_load(c, __ATOMIC_RELAXED, __HIP_MEMORY_SCOPE_AGENT) < 64u)
      __builtin_amdgcn_s_sleep(1);
    __threadfence();   // acquire
  }
  __syncthreads();
}

// ---------------------------------------------------------------------------
// Phase 1: instnorm stats (redundant per block, x L2-resident) + proj1.
// Block = (b, u): 16 rows n = u*16..+16. Thread t = r*16 + h*4 + dup:
// r = t>>4, h = (t>>2)&3, dup = t&3 (o-quarter). shfl over dup for src/dst.
// ---------------------------------------------------------------------------
__device__ __forceinline__ void proj1_body(
    int b, int u, int t, Smem& sm,
    const float* __restrict__ x, const float* __restrict__ w1,
    const float* __restrict__ asrc, const float* __restrict__ adst,
    short* __restrict__ hpT_hi, short* __restrict__ hpT_lo,
    float* __restrict__ src, float* __restrict__ dst,
    float* __restrict__ statsAcc)
{
  const int r = t >> 4, h = (t >> 2) & 3, dup = t & 3;

  if (u == 0 && t < 128) statsAcc[b * 128 + t] = 0.f;

  for (int idx = t; idx < 4 * F1n * F0; idx += 256) {
    const int f = idx & 31, ho = idx >> 5;
    sm.p1.wt[idx] = w1[((ho >> 4) * F0 + f) * F1n + (ho & 15)];
  }
  if (t < 64) { sm.p1.as[t] = asrc[t]; sm.p1.ad[t] = adst[t]; }

  const float* xb = x + (size_t)b * Nn * F0;
  {
    const int c = t & 31, seg = t >> 5;
    float sum = 0.f, ssq = 0.f;
#pragma unroll 8
    for (int nn = seg; nn < Nn; nn += 8) {
      float v = xb[nn * F0 + c];
      sum += v; ssq += v * v;
    }
    sm.p1.sum[seg][c] = sum; sm.p1.ssq[seg][c] = ssq;
  }
  __syncthreads();
  if (t < 32) {
    float s = 0.f, q = 0.f;
#pragma unroll
    for (int k = 0; k < 8; k++) { s += sm.p1.sum[k][t]; q += sm.p1.ssq[k][t]; }
    const float mean = s * (1.f / Nn);
    const float var  = fmaf(-mean, mean, q * (1.f / Nn));
    sm.p1.mean[t] = mean;
    sm.p1.rstd[t] = rsqrtf(var + EPS);
  }
  __syncthreads();

  // normalize 16 rows into LDS (512 elements, 2 per thread)
  const int n0 = u * 16;
  for (int idx = t; idx < 16 * F0; idx += 256) {
    const int rr = idx >> 5, f = idx & 31;
    sm.p1.x[rr][f] = (xb[(n0 + rr) * F0 + f] - sm.p1.mean[f]) * sm.p1.rstd[f];
  }
  __syncthreads();

  const int n  = n0 + r;
  const int bh = b * 4 + h;
  float sp = 0.f, dp = 0.f;
#pragma unroll
  for (int k = 0; k < 4; k++) {
    const int o = dup * 4 + k;
    float acc = 0.f;
#pragma unroll
    for (int f = 0; f < F0; f++)
      acc = fmaf(sm.p1.x[r][f], sm.p1.wt[(h * F1n + o) * F0 + f], acc);
    sp = fmaf(acc, sm.p1.as[h * F1n + o], sp);
    dp = fmaf(acc, sm.p1.ad[h * F1n + o], dp);
    const _Float16 hh = (_Float16)acc;
    const _Float16 hl = (_Float16)(acc - (float)hh);
    const size_t idx = ((size_t)bh * F1n + o) * Nn + n;
    hpT_hi[idx] = __builtin_bit_cast(short, hh);
    hpT_lo[idx] = __builtin_bit_cast(short, hl);
  }
  sp += __shfl_xor(sp, 1); dp += __shfl_xor(dp, 1);
  sp += __shfl_xor(sp, 2); dp += __shfl_xor(dp, 2);
  if (dup == 0) {
    src[bh * Nn + n] = sp;
    dst[bh * Nn + n] = dp;
  }
}

// ---------------------------------------------------------------------------
// Phase 2: attn1 (fp16 MFMA PV, V hi+lo) + bias + elu -> x1; atomic stats.
// Block = (b, u): h = u>>4, tile = u&15; 4 waves x 16 rows.
// ---------------------------------------------------------------------------
__device__ __forceinline__ void attn1_body(
    int b, int u, int t, Smem& sm,
    const short* __restrict__ hpT_hi, const short* __restrict__ hpT_lo,
    const float* __restrict__ src, const float* __restrict__ dst,
    const float* __restrict__ bias, float* __restrict__ x1,
    float* __restrict__ statsAcc)
{
  const int bh   = b * 4 + (u >> 4);
  const int tile = u & 15;
  const int w    = t >> 6;
  const int l    = t & 63;
  const int col  = l & 15;
  const int ks   = l >> 4;

  const float* dptr = dst + bh * Nn;
  float lm = -1e30f;
  for (int j = t; j < Nn; j += 256) { float v = dptr[j]; sm.p2.dst[j] = v; lm = fmaxf(lm, v); }
#pragma unroll
  for (int mask = 32; mask >= 1; mask >>= 1) lm = fmaxf(lm, __shfl_xor(lm, mask));
  if (l == 0) sm.p2.red[w] = lm;
  __syncthreads();
  const float dmax = fmaxf(fmaxf(sm.p2.red[0], sm.p2.red[1]),
                           fmaxf(sm.p2.red[2], sm.p2.red[3]));

  const int i0 = tile * 64 + w * 16;
  const float si = src[bh * Nn + i0 + col];
  const float t0v = si + dmax;
  const float em  = fmaxf(t0v, ALPHA * t0v) * LOG2E;   // lrelu monotone => row max

  auto pexp = [&](float dv) {
    const float tt = si + dv;
    const float uu = fmaxf(tt, ALPHA * tt);
    return exp2f(fmaf(uu, LOG2E, -em));
  };

  const half8* bph = reinterpret_cast<const half8*>(hpT_hi + (size_t)bh * F1n * Nn);
  const half8* bpl = reinterpret_cast<const half8*>(hpT_lo + (size_t)bh * F1n * Nn);
  f32x4 acc = {0.f, 0.f, 0.f, 0.f};
  float psum = 0.f;

#pragma unroll 2
  for (int jb = 0; jb < 32; ++jb) {
    const int jo = (jb << 5) | (ks << 3);
    const float4 dA = *reinterpret_cast<const float4*>(&sm.p2.dst[jo]);
    const float4 dB = *reinterpret_cast<const float4*>(&sm.p2.dst[jo + 4]);
    half8 af;
    const _Float16 q0 = (_Float16)pexp(dA.x); af[0] = q0;
    const _Float16 q1 = (_Float16)pexp(dA.y); af[1] = q1;
    const _Float16 q2 = (_Float16)pexp(dA.z); af[2] = q2;
    const _Float16 q3 = (_Float16)pexp(dA.w); af[3] = q3;
    const _Float16 q4 = (_Float16)pexp(dB.x); af[4] = q4;
    const _Float16 q5 = (_Float16)pexp(dB.y); af[5] = q5;
    const _Float16 q6 = (_Float16)pexp(dB.z); af[6] = q6;
    const _Float16 q7 = (_Float16)pexp(dB.w); af[7] = q7;
    psum += (((float)q0 + (float)q1) + ((float)q2 + (float)q3)) +
            (((float)q4 + (float)q5) + ((float)q6 + (float)q7));

    const half8 bh8 = bph[col * 128 + (jb << 2) + ks];
    const half8 bl8 = bpl[col * 128 + (jb << 2) + ks];
    acc = __builtin_amdgcn_mfma_f32_16x16x32_f16(af, bh8, acc, 0, 0, 0);
    acc = __builtin_amdgcn_mfma_f32_16x16x32_f16(af, bl8, acc, 0, 0, 0);
  }

  psum += __shfl_xor(psum, 16);
  psum += __shfl_xor(psum, 32);
  if (l < 16) sm.p2.ps[w][col] = psum;
  __syncthreads();

  const int h = u >> 4;
  const float bc = bias[col];
  float sv = 0.f, sq = 0.f;
#pragma unroll
  for (int r = 0; r < 4; ++r) {
    const int row = ks * 4 + r;
    const float inv = 1.f / sm.p2.ps[w][row];
    float v = fmaf(acc[r], inv, bc);
    v = v > 0.f ? v : exp2f(v * LOG2E) - 1.f;   // elu
    x1[((size_t)(b * Nn + i0 + row)) * FH + h * F1n + col] = v;
    sv += v; sq += v * v;
  }
  sv += __shfl_xor(sv, 16); sq += __shfl_xor(sq, 16);
  sv += __shfl_xor(sv, 32); sq += __shfl_xor(sq, 32);
  if (l < 16) {
    const int ch = h * F1n + col;
    atomicAdd(&statsAcc[b * 128 + ch], sv);
    atomicAdd(&statsAcc[b * 128 + 64 + ch], sq);
  }
}

// ---------------------------------------------------------------------------
// Phase 3: proj2 from statsAcc. Block = (b, u): 16 rows n = u*16..+16.
// Thread t = r*16 + g: r = t>>4, g = t&15 (2 outputs o = 2g, 2g+1).
// ---------------------------------------------------------------------------
__device__ __forceinline__ void proj2_body(
    int b, int u, int t, Smem& sm,
    const float* __restrict__ x1, const float* __restrict__ statsAcc,
    const float* __restrict__ w2,
    const float* __restrict__ asrc, const float* __restrict__ adst,
    short* __restrict__ hpT_hi, short* __restrict__ hpT_lo,
    float* __restrict__ src, float* __restrict__ dst)
{
  const int r = t >> 4, g = t & 15;

  for (int idx = t; idx < F2n * FH; idx += 256) {
    const int f = idx & 63, o = idx >> 6;
    sm.p3.wt[idx] = w2[f * F2n + o];
  }
  if (t < F2n) { sm.p3.as[t] = asrc[t]; sm.p3.ad[t] = adst[t]; }
  if (t < 64) {
    const float s = statsAcc[b * 128 + t];
    const float q = statsAcc[b * 128 + 64 + t];
    const float mean = s * (1.f / Nn);
    const float var  = fmaf(-mean, mean, q * (1.f / Nn));
    sm.p3.mean[t] = mean;
    sm.p3.rstd[t] = rsqrtf(var + EPS);
  }
  __syncthreads();

  const int n0 = u * 16;
  for (int idx = t; idx < 16 * FH; idx += 256) {
    const int rr = idx >> 6, f = idx & 63;
    sm.p3.x[rr][f] = (x1[((size_t)(b * Nn + n0 + rr)) * FH + f] - sm.p3.mean[f]) * sm.p3.rstd[f];
  }
  __syncthreads();

  const int n    = n0 + r;
  const int base = b * Nn + n;
  float sp = 0.f, dp = 0.f;
#pragma unroll
  for (int k = 0; k < 2; k++) {
    const int o = g * 2 + k;
    float acc = 0.f;
#pragma unroll
    for (int f = 0; f < FH; f++)
      acc = fmaf(sm.p3.x[r][f], sm.p3.wt[o * FH + f], acc);
    sp = fmaf(acc, sm.p3.as[o], sp);
    dp = fmaf(acc, sm.p3.ad[o], dp);
    const _Float16 hh = (_Float16)acc;
    const _Float16 hl = (_Float16)(acc - (float)hh);
    const size_t idx = ((size_t)b * F2n + o) * Nn + n;
    hpT_hi[idx] = __builtin_bit_cast(short, hh);
    hpT_lo[idx] = __builtin_bit_cast(short, hl);
  }
  sp += __shfl_xor(sp, 1); dp += __shfl_xor(dp, 1);
  sp += __shfl_xor(sp, 2); dp += __shfl_xor(dp, 2);
  sp += __shfl_xor(sp, 4); dp += __shfl_xor(dp, 4);
  sp += __shfl_xor(sp, 8); dp += __shfl_xor(dp, 8);
  if (g == 0) {
    src[base] = sp;
    dst[base] = dp;
  }
}

// ---------------------------------------------------------------------------
// Phase 4: attn2 (fp16 MFMA PV, V hi+lo) + bias -> out.
// Block = (b, u): tile = u (16 rows); wave jq owns a j-quarter.
// ---------------------------------------------------------------------------
__device__ __forceinline__ void attn2_body(
    int b, int u, int t, Smem& sm,
    const short* __restrict__ hpT_hi, const short* __restrict__ hpT_lo,
    const float* __restrict__ src, const float* __restrict__ dst,
    const float* __restrict__ bias, float* __restrict__ out)
{
  const int tile = u;
  const int jq   = t >> 6;
  const int l    = t & 63;
  const int col  = l & 15;
  const int ks   = l >> 4;

  const float* dptr = dst + b * Nn;
  float lm = -1e30f;
  for (int j = t; j < Nn; j += 256) { float v = dptr[j]; sm.p4.dst[j] = v; lm = fmaxf(lm, v); }
#pragma unroll
  for (int mask = 32; mask >= 1; mask >>= 1) lm = fmaxf(lm, __shfl_xor(lm, mask));
  if (l == 0) sm.p4.red[jq] = lm;
  __syncthreads();
  const float dmax = fmaxf(fmaxf(sm.p4.red[0], sm.p4.red[1]),
                           fmaxf(sm.p4.red[2], sm.p4.red[3]));

  const int i0 = tile * 16;
  const float si = src[b * Nn + i0 + col];
  const float t0v = si + dmax;
  const float em  = fmaxf(t0v, ALPHA * t0v) * LOG2E;

  auto pexp = [&](float dv) {
    const float tt = si + dv;
    const float uu = fmaxf(tt, ALPHA * tt);
    return exp2f(fmaf(uu, LOG2E, -em));
  };

  const half8* bph = reinterpret_cast<const half8*>(hpT_hi + (size_t)b * F2n * Nn);
  const half8* bpl = reinterpret_cast<const half8*>(hpT_lo + (size_t)b * F2n * Nn);
  f32x4 acc0 = {0.f, 0.f, 0.f, 0.f};
  f32x4 acc1 = {0.f, 0.f, 0.f, 0.f};
  float psum = 0.f;

#pragma unroll 2
  for (int kb = 0; kb < 8; ++kb) {
    const int jb = jq * 8 + kb;
    const int jo = (jb << 5) | (ks << 3);
    const float4 dA = *reinterpret_cast<const float4*>(&sm.p4.dst[jo]);
    const float4 dB = *reinterpret_cast<const float4*>(&sm.p4.dst[jo + 4]);
    half8 af;
    const _Float16 q0 = (_Float16)pexp(dA.x); af[0] = q0;
    const _Float16 q1 = (_Float16)pexp(dA.y); af[1] = q1;
    const _Float16 q2 = (_Float16)pexp(dA.z); af[2] = q2;
    const _Float16 q3 = (_Float16)pexp(dA.w); af[3] = q3;
    const _Float16 q4 = (_Float16)pexp(dB.x); af[4] = q4;
    const _Float16 q5 = (_Float16)pexp(dB.y); af[5] = q5;
    const _Float16 q6 = (_Float16)pexp(dB.z); af[6] = q6;
    const _Float16 q7 = (_Float16)pexp(dB.w); af[7] = q7;
    psum += (((float)q0 + (float)q1) + ((float)q2 + (float)q3)) +
            (((float)q4 + (float)q5) + ((float)q6 + (float)q7));

    const half8 bh0 = bph[col * 128 + (jb << 2) + ks];
    const half8 bl0 = bpl[col * 128 + (jb << 2) + ks];
    const half8 bh1 = bph[(col + 16) * 128 + (jb << 2) + ks];
    const half8 bl1 = bpl[(col + 16) * 128 + (jb << 2) + ks];
    acc0 = __builtin_amdgcn_mfma_f32_16x16x32_f16(af, bh0, acc0, 0, 0, 0);
    acc0 = __builtin_amdgcn_mfma_f32_16x16x32_f16(af, bl0, acc0, 0, 0, 0);
    acc1 = __builtin_amdgcn_mfma_f32_16x16x32_f16(af, bh1, acc1, 0, 0, 0);
    acc1 = __builtin_amdgcn_mfma_f32_16x16x32_f16(af, bl1, acc1, 0, 0, 0);
  }

  if (jq > 0) {
#pragma unroll
    for (int r = 0; r < 4; ++r) {
      sm.p4.comb[jq - 1][l][r]     = acc0[r];
      sm.p4.comb[jq - 1][l][r + 4] = acc1[r];
    }
    sm.p4.comb[jq - 1][l][8] = psum;
  }
  __syncthreads();

  if (jq == 0) {
#pragma unroll
    for (int g = 0; g < 3; ++g) {
#pragma unroll
      for (int r = 0; r < 4; ++r) {
        acc0[r] += sm.p4.comb[g][l][r];
        acc1[r] += sm.p4.comb[g][l][r + 4];
      }
      psum += sm.p4.comb[g][l][8];
    }
    psum += __shfl_xor(psum, 16);
    psum += __shfl_xor(psum, 32);
    if (l < 16) sm.p4.ps[col] = psum;   // same-wave LDS: ordered

    const float bc0 = bias[col];
    const float bc1 = bias[col + 16];
#pragma unroll
    for (int r = 0; r < 4; ++r) {
      const int row = ks * 4 + r;
      const float inv = 1.f / sm.p4.ps[row];
      float* op = out + ((size_t)(b * Nn + i0 + row)) * F2n;
      op[col]      = fmaf(acc0[r], inv, bc0);
      op[col + 16] = fmaf(acc1[r], inv, bc1);
    }
  }
}

// ---------------------------------------------------------------------------
// Fused persistent kernel: 1024 blocks, per-batch barriers (64 blocks each).
// ---------------------------------------------------------------------------
__global__ __launch_bounds__(256, 4) void k_fused(
    const float* __restrict__ x, const float* __restrict__ w1,
    const float* __restrict__ as1, const float* __restrict__ ad1,
    const float* __restrict__ b1,  const float* __restrict__ w2,
    const float* __restrict__ as2, const float* __restrict__ ad2,
    const float* __restrict__ b2,
    short* hpT1_hi, short* hpT1_lo, short* hpT2_hi, short* hpT2_lo,
    float* x1, float* src1, float* dst1, float* src2, float* dst2,
    float* statsA, float* out, unsigned* bars)
{
  __shared__ Smem sm;
  const int bid = blockIdx.x, t = threadIdx.x;
  const int b = bid >> 6, u = bid & 63;

  proj1_body(b, u, t, sm, x, w1, as1, ad1, hpT1_hi, hpT1_lo, src1, dst1, statsA);
  batch_barrier(bars + ((0 * 16 + b) << 5));

  attn1_body(b, u, t, sm, hpT1_hi, hpT1_lo, src1, dst1, b1, x1, statsA);
  batch_barrier(bars + ((1 * 16 + b) << 5));

  proj2_body(b, u, t, sm, x1, statsA, w2, as2, ad2, hpT2_hi, hpT2_lo, src2, dst2);
  batch_barrier(bars + ((2 * 16 + b) << 5));

  attn2_body(b, u, t, sm, hpT2_hi, hpT2_lo, src2, dst2, b2, out);
}

// ---------------------------------------------------------------------------
// Fallback standalone kernels (same bodies), 1024 blocks each.
// ---------------------------------------------------------------------------
__global__ __launch_bounds__(256) void k_proj1(
    const float* x, const float* w1, const float* as1, const float* ad1,
    short* hpT_hi, short* hpT_lo, float* src, float* dst, float* statsA)
{ __shared__ Smem sm; proj1_body(blockIdx.x >> 6, blockIdx.x & 63, threadIdx.x, sm, x, w1, as1, ad1, hpT_hi, hpT_lo, src, dst, statsA); }

__global__ __launch_bounds__(256) void k_attn1(
    const short* hpT_hi, const short* hpT_lo, const float* src, const float* dst,
    const float* bias, float* x1, float* statsA)
{ __shared__ Smem sm; attn1_body(blockIdx.x >> 6, blockIdx.x & 63, threadIdx.x, sm, hpT_hi, hpT_lo, src, dst, bias, x1, statsA); }

__global__ __launch_bounds__(256) void k_proj2(
    const float* x1, const float* statsA, const float* w2,
    const float* as2, const float* ad2,
    short* hpT_hi, short* hpT_lo, float* src, float* dst)
{ __shared__ Smem sm; proj2_body(blockIdx.x >> 6, blockIdx.x & 63, threadIdx.x, sm, x1, statsA, w2, as2, ad2, hpT_hi, hpT_lo, src, dst); }

__global__ __launch_bounds__(256) void k_attn2(
    const short* hpT_hi, const short* hpT_lo, const float* src, const float* dst,
    const float* bias, float* out)
{ __shared__ Smem sm; attn2_body(blockIdx.x >> 6, blockIdx.x & 63, threadIdx.x, sm, hpT_hi, hpT_lo, src, dst, bias, out); }

extern "C" void kernel_launch(void* const* d_in, const int* in_sizes, int n_in,
                              void* d_out, int out_size, void* d_ws, size_t ws_size,
                              hipStream_t stream) {
  (void)in_sizes; (void)n_in; (void)out_size; (void)ws_size;
  const float* x   = (const float*)d_in[0];
  const float* w1  = (const float*)d_in[1];
  const float* as1 = (const float*)d_in[2];
  const float* ad1 = (const float*)d_in[3];
  const float* b1  = (const float*)d_in[4];
  const float* w2  = (const float*)d_in[5];
  const float* as2 = (const float*)d_in[6];
  const float* ad2 = (const float*)d_in[7];
  const float* b2  = (const float*)d_in[8];
  float* out = (float*)d_out;

  float* ws = (float*)d_ws;
  short* hpT1_hi = (short*)ws;                         // 64*16*1024 sh = 524288 f
  short* hpT1_lo = (short*)(ws + 524288);              // 524288 f
  short* hpT2_hi = (short*)(ws + 1048576);             // 16*32*1024 sh = 262144 f
  short* hpT2_lo = (short*)(ws + 1048576 + 262144);    // 262144 f
  float* x1      = ws + 1048576 + 524288;              // 1048576 f
  float* src1    = x1 + 1048576;                       // 65536
  float* dst1    = src1 + 65536;                       // 65536
  float* src2    = dst1 + 65536;                       // 16384
  float* dst2    = src2 + 16384;                       // 16384
  float* statsA  = dst2 + 16384;                       // 2048
  unsigned* bars = (unsigned*)(statsA + 2048);         // 3*16 padded counters

  (void)hipMemsetAsync(bars, 0, 3 * 16 * 32 * sizeof(unsigned), stream);

  int maxB = 0;
  hipError_t e = hipOccupancyMaxActiveBlocksPerMultiprocessor(&maxB, k_fused, 256, 0);
  if (e == hipSuccess && maxB >= 4) {
    k_fused<<<1024, 256, 0, stream>>>(x, w1, as1, ad1, b1, w2, as2, ad2, b2,
                                      hpT1_hi, hpT1_lo, hpT2_hi, hpT2_lo,
                                      x1, src1, dst1, src2, dst2, statsA, out, bars);
  } else {
    k_proj1<<<1024, 256, 0, stream>>>(x, w1, as1, ad1, hpT1_hi, hpT1_lo, src1, dst1, statsA);
    k_attn1<<<1024, 256, 0, stream>>>(hpT1_hi, hpT1_lo, src1, dst1, b1, x1, statsA);
    k_proj2<<<1024, 256, 0, stream>>>(x1, statsA, w2, as2, ad2, hpT2_hi, hpT2_lo, src2, dst2);
    k_attn2<<<1024, 256, 0, stream>>>(hpT2_hi, hpT2_lo, src2, dst2, b2, out);
  }
}

// Round 12
// 142.317 us; speedup vs baseline: 1.2080x; 1.2080x over previous
//
#include <hip/hip_runtime.h>

// ProxemicsFieldGenerator: 2-layer GAT on dense graph.
// b=16, n=1024, f0=32, h0=4, f1=16, FH=64, f2=32, h1=1.
// FINAL (revert to R7 config — best measured 142.3 us):
// 4-kernel pipeline:
//  K1 proj1: per-block redundant instnorm stats (L2-cached) + projection ->
//            hpT1 hi/lo fp16 + src1/dst1; also zeroes the layer-2 stats accum.
//  K2 attn1: fp16-MFMA PV + bias + elu -> x1; atomically accumulates layer-2
//            per-channel (sum, ssq) into statsAcc.
//  K3 proj2: finalizes stats from statsAcc (128 floats) + projection.
//  K4 attn2: fp16-MFMA PV + bias -> out.
// Persistent-kernel fusion (R9 global barrier, R11 per-batch barriers) was
// tried and measured SLOWER (146/172 us): spin-wait + phase serialization
// outweigh the ~5 us/boundary launch cost. Remaining time is harness
// poison-fill (43 us @ 6.3 TB/s HBM roofline) + launch/restore floor.

namespace {
constexpr int Nn  = 1024;
constexpr int F0  = 32;
constexpr int F1n = 16;
constexpr int FH  = 64;   // h0 * f1
constexpr int F2n = 32;
constexpr float LOG2E = 1.4426950408889634f;
constexpr float EPS   = 1e-5f;
constexpr float ALPHA = 0.2f;
}

typedef __attribute__((ext_vector_type(8))) _Float16 half8;
typedef __attribute__((ext_vector_type(4))) float f32x4;

// ---------------------------------------------------------------------------
// K1 proj1: grid = 16 b * 16 tiles(64 rows), block = 256 (r = t&63, h = t>>6)
// ---------------------------------------------------------------------------
__global__ __launch_bounds__(256) void k_proj1(
    const float* __restrict__ x, const float* __restrict__ w1,
    const float* __restrict__ asrc, const float* __restrict__ adst,
    short* __restrict__ hpT_hi, short* __restrict__ hpT_lo,
    float* __restrict__ src, float* __restrict__ dst,
    float* __restrict__ statsAcc)
{
  const int b    = blockIdx.x >> 4;
  const int tile = blockIdx.x & 15;
  const int t    = threadIdx.x;
  const int r    = t & 63, h = t >> 6;

  __shared__ float  s_sum[8][33];
  __shared__ float  s_ssq[8][33];
  __shared__ float  s_mean[32], s_rstd[32];
  __shared__ float4 s_wt4[4 * F1n * (F0 / 4)];   // [h][o][f/4]
  __shared__ float  s_as[64], s_ad[64];

  // zero the layer-2 stats accumulator (ws is poisoned each call)
  if (tile == 0 && t < 128) statsAcc[b * 128 + t] = 0.f;

  // --- weights / attention vectors to LDS ---
  float* s_wt = reinterpret_cast<float*>(s_wt4);
  for (int idx = t; idx < 4 * F1n * F0; idx += 256) {
    const int f = idx & 31, ho = idx >> 5;
    s_wt[idx] = w1[((ho >> 4) * F0 + f) * F1n + (ho & 15)];
  }
  if (t < 64) { s_as[t] = asrc[t]; s_ad[t] = adst[t]; }

  // --- redundant per-block stats over all 1024 rows (x is L2/L3-resident) ---
  const float* xb = x + (size_t)b * Nn * F0;
  {
    const int c = t & 31, seg = t >> 5;
    float sum = 0.f, ssq = 0.f;
#pragma unroll 8
    for (int nn = seg; nn < Nn; nn += 8) {
      float v = xb[nn * F0 + c];
      sum += v; ssq += v * v;
    }
    s_sum[seg][c] = sum; s_ssq[seg][c] = ssq;
  }
  __syncthreads();
  if (t < 32) {
    float s = 0.f, q = 0.f;
#pragma unroll
    for (int k = 0; k < 8; k++) { s += s_sum[k][t]; q += s_ssq[k][t]; }
    const float mean = s * (1.f / Nn);
    const float var  = fmaf(-mean, mean, q * (1.f / Nn));
    s_mean[t] = mean;
    s_rstd[t] = rsqrtf(var + EPS);
  }
  __syncthreads();

  // --- one row per thread, x in registers ---
  const int n  = tile * 64 + r;
  const int bh = b * 4 + h;
  float4 xr[F0 / 4];
  const float4* xrow = reinterpret_cast<const float4*>(xb + (size_t)n * F0);
#pragma unroll
  for (int k = 0; k < F0 / 4; k++) {
    float4 v = xrow[k];
    v.x = (v.x - s_mean[k * 4 + 0]) * s_rstd[k * 4 + 0];
    v.y = (v.y - s_mean[k * 4 + 1]) * s_rstd[k * 4 + 1];
    v.z = (v.z - s_mean[k * 4 + 2]) * s_rstd[k * 4 + 2];
    v.w = (v.w - s_mean[k * 4 + 3]) * s_rstd[k * 4 + 3];
    xr[k] = v;
  }

  float sdot = 0.f, ddot = 0.f;
#pragma unroll 1
  for (int o = 0; o < F1n; o++) {
    float acc = 0.f;
#pragma unroll
    for (int k = 0; k < F0 / 4; k++) {
      const float4 wv = s_wt4[(h * F1n + o) * (F0 / 4) + k];
      const float4 xv = xr[k];
      acc = fmaf(xv.x, wv.x, acc); acc = fmaf(xv.y, wv.y, acc);
      acc = fmaf(xv.z, wv.z, acc); acc = fmaf(xv.w, wv.w, acc);
    }
    sdot = fmaf(acc, s_as[h * F1n + o], sdot);
    ddot = fmaf(acc, s_ad[h * F1n + o], ddot);
    const _Float16 hh = (_Float16)acc;
    const _Float16 hl = (_Float16)(acc - (float)hh);
    const size_t idx = ((size_t)bh * F1n + o) * Nn + n;
    hpT_hi[idx] = __builtin_bit_cast(short, hh);
    hpT_lo[idx] = __builtin_bit_cast(short, hl);
  }
  src[bh * Nn + n] = sdot;
  dst[bh * Nn + n] = ddot;
}

// ---------------------------------------------------------------------------
// K2 attn1: fp16 MFMA PV (V hi+lo) + bias + elu -> x1; atomic layer-2 stats.
// grid = 64 bh * 16 tiles = 1024 blocks, block 256 = 4 waves x 16 rows.
// ---------------------------------------------------------------------------
__global__ __launch_bounds__(256) void k_attn1(
    const short* __restrict__ hpT_hi, const short* __restrict__ hpT_lo,
    const float* __restrict__ src, const float* __restrict__ dst,
    const float* __restrict__ bias, float* __restrict__ x1,
    float* __restrict__ statsAcc)
{
  const int bh   = blockIdx.x >> 4;
  const int tile = blockIdx.x & 15;
  const int t    = threadIdx.x;
  const int w    = t >> 6;
  const int l    = t & 63;
  const int col  = l & 15;      // A-row (= query row) and C/D col (= channel)
  const int ks   = l >> 4;      // k-slot 0..3

  __shared__ float s_dst[Nn];
  __shared__ float s_red[4];
  __shared__ float s_ps[4][16];

  const float* dp = dst + bh * Nn;
  float lm = -1e30f;
  for (int j = t; j < Nn; j += 256) { float v = dp[j]; s_dst[j] = v; lm = fmaxf(lm, v); }
#pragma unroll
  for (int mask = 32; mask >= 1; mask >>= 1) lm = fmaxf(lm, __shfl_xor(lm, mask));
  if (l == 0) s_red[w] = lm;
  __syncthreads();
  const float dmax = fmaxf(fmaxf(s_red[0], s_red[1]), fmaxf(s_red[2], s_red[3]));

  const int i0 = tile * 64 + w * 16;
  const float si = src[bh * Nn + i0 + col];
  const float t0v = si + dmax;
  const float em  = fmaxf(t0v, ALPHA * t0v) * LOG2E;   // lrelu monotone => row max

  auto pexp = [&](float dv) {
    const float tt = si + dv;
    const float u  = fmaxf(tt, ALPHA * tt);
    return exp2f(fmaf(u, LOG2E, -em));
  };

  const half8* bph = reinterpret_cast<const half8*>(hpT_hi + (size_t)bh * F1n * Nn);
  const half8* bpl = reinterpret_cast<const half8*>(hpT_lo + (size_t)bh * F1n * Nn);
  f32x4 acc = {0.f, 0.f, 0.f, 0.f};
  float psum = 0.f;

#pragma unroll 2
  for (int jb = 0; jb < 32; ++jb) {
    const int jo = (jb << 5) | (ks << 3);
    const float4 dA = *reinterpret_cast<const float4*>(&s_dst[jo]);
    const float4 dB = *reinterpret_cast<const float4*>(&s_dst[jo + 4]);
    half8 af;
    const _Float16 q0 = (_Float16)pexp(dA.x); af[0] = q0;
    const _Float16 q1 = (_Float16)pexp(dA.y); af[1] = q1;
    const _Float16 q2 = (_Float16)pexp(dA.z); af[2] = q2;
    const _Float16 q3 = (_Float16)pexp(dA.w); af[3] = q3;
    const _Float16 q4 = (_Float16)pexp(dB.x); af[4] = q4;
    const _Float16 q5 = (_Float16)pexp(dB.y); af[5] = q5;
    const _Float16 q6 = (_Float16)pexp(dB.z); af[6] = q6;
    const _Float16 q7 = (_Float16)pexp(dB.w); af[7] = q7;
    // psum from the ROUNDED weights => consistent normalization
    psum += (((float)q0 + (float)q1) + ((float)q2 + (float)q3)) +
            (((float)q4 + (float)q5) + ((float)q6 + (float)q7));

    const half8 bh8 = bph[col * 128 + (jb << 2) + ks];
    const half8 bl8 = bpl[col * 128 + (jb << 2) + ks];
    acc = __builtin_amdgcn_mfma_f32_16x16x32_f16(af, bh8, acc, 0, 0, 0);
    acc = __builtin_amdgcn_mfma_f32_16x16x32_f16(af, bl8, acc, 0, 0, 0);
  }

  psum += __shfl_xor(psum, 16);
  psum += __shfl_xor(psum, 32);
  if (l < 16) s_ps[w][col] = psum;
  __syncthreads();

  const int b = bh >> 2, h = bh & 3;
  const float bc = bias[col];
  float sv = 0.f, sq = 0.f;
#pragma unroll
  for (int r = 0; r < 4; ++r) {
    const int row = ks * 4 + r;
    const float inv = 1.f / s_ps[w][row];
    float v = fmaf(acc[r], inv, bc);
    v = v > 0.f ? v : exp2f(v * LOG2E) - 1.f;   // elu
    x1[((size_t)(b * Nn + i0 + row)) * FH + h * F1n + col] = v;
    sv += v; sq += v * v;
  }
  // layer-2 instnorm partial stats: reduce over ks groups -> 16-row sums/col
  sv += __shfl_xor(sv, 16); sq += __shfl_xor(sq, 16);
  sv += __shfl_xor(sv, 32); sq += __shfl_xor(sq, 32);
  if (l < 16) {
    const int ch = h * F1n + col;
    atomicAdd(&statsAcc[b * 128 + ch], sv);
    atomicAdd(&statsAcc[b * 128 + 64 + ch], sq);
  }
}

// ---------------------------------------------------------------------------
// K3 proj2: grid = 16 b * 16 tiles(64 rows), block = 256 (r = t&63, og = t>>6)
// Stats from statsAcc (accumulated by attn1). x1 row in registers.
// ---------------------------------------------------------------------------
__global__ __launch_bounds__(256) void k_proj2(
    const float* __restrict__ x1, const float* __restrict__ statsAcc,
    const float* __restrict__ w2,
    const float* __restrict__ asrc, const float* __restrict__ adst,
    short* __restrict__ hpT_hi, short* __restrict__ hpT_lo,
    float* __restrict__ src, float* __restrict__ dst)
{
  const int b    = blockIdx.x >> 4;
  const int tile = blockIdx.x & 15;
  const int t    = threadIdx.x;
  const int r    = t & 63, og = t >> 6;

  __shared__ float  s_mean[64], s_rstd[64];
  __shared__ float4 s_wt4[F2n * (FH / 4)];   // [o][f/4]
  __shared__ float  s_as[F2n], s_ad[F2n];
  __shared__ float  s_sd[4][64][2];

  float* s_wt = reinterpret_cast<float*>(s_wt4);
  for (int idx = t; idx < F2n * FH; idx += 256) {
    const int f = idx & 63, o = idx >> 6;
    s_wt[idx] = w2[f * F2n + o];
  }
  if (t < F2n) { s_as[t] = asrc[t]; s_ad[t] = adst[t]; }
  if (t < 64) {
    const float s = statsAcc[b * 128 + t];
    const float q = statsAcc[b * 128 + 64 + t];
    const float mean = s * (1.f / Nn);
    const float var  = fmaf(-mean, mean, q * (1.f / Nn));
    s_mean[t] = mean;
    s_rstd[t] = rsqrtf(var + EPS);
  }
  __syncthreads();

  const int n    = tile * 64 + r;
  const int base = b * Nn + n;
  float4 xr[FH / 4];
  const float4* xrow = reinterpret_cast<const float4*>(
      x1 + (size_t)b * Nn * FH + (size_t)n * FH);
#pragma unroll
  for (int k = 0; k < FH / 4; k++) {
    float4 v = xrow[k];
    v.x = (v.x - s_mean[k * 4 + 0]) * s_rstd[k * 4 + 0];
    v.y = (v.y - s_mean[k * 4 + 1]) * s_rstd[k * 4 + 1];
    v.z = (v.z - s_mean[k * 4 + 2]) * s_rstd[k * 4 + 2];
    v.w = (v.w - s_mean[k * 4 + 3]) * s_rstd[k * 4 + 3];
    xr[k] = v;
  }

  float sdot = 0.f, ddot = 0.f;
#pragma unroll 1
  for (int oo = 0; oo < 8; oo++) {
    const int o = og * 8 + oo;
    float acc = 0.f;
#pragma unroll
    for (int k = 0; k < FH / 4; k++) {
      const float4 wv = s_wt4[o * (FH / 4) + k];
      const float4 xv = xr[k];
      acc = fmaf(xv.x, wv.x, acc); acc = fmaf(xv.y, wv.y, acc);
      acc = fmaf(xv.z, wv.z, acc); acc = fmaf(xv.w, wv.w, acc);
    }
    sdot = fmaf(acc, s_as[o], sdot);
    ddot = fmaf(acc, s_ad[o], ddot);
    const _Float16 hh = (_Float16)acc;
    const _Float16 hl = (_Float16)(acc - (float)hh);
    const size_t idx = ((size_t)b * F2n + o) * Nn + n;
    hpT_hi[idx] = __builtin_bit_cast(short, hh);
    hpT_lo[idx] = __builtin_bit_cast(short, hl);
  }

  s_sd[og][r][0] = sdot; s_sd[og][r][1] = ddot;
  __syncthreads();
  if (og == 0) {
    float s = 0.f, d = 0.f;
#pragma unroll
    for (int g = 0; g < 4; g++) { s += s_sd[g][r][0]; d += s_sd[g][r][1]; }
    src[base] = s;
    dst[base] = d;
  }
}

// ---------------------------------------------------------------------------
// K4 attn2: fp16 MFMA PV (V hi+lo) + bias -> out [b,n,32]
// grid = 16 b * 64 tiles(16 rows) = 1024 blocks, block 256 = 4 waves.
// ---------------------------------------------------------------------------
__global__ __launch_bounds__(256) void k_attn2(
    const short* __restrict__ hpT_hi, const short* __restrict__ hpT_lo,
    const float* __restrict__ src, const float* __restrict__ dst,
    const float* __restrict__ bias, float* __restrict__ out)
{
  const int b    = blockIdx.x >> 6;
  const int tile = blockIdx.x & 63;
  const int t    = threadIdx.x;
  const int jq   = t >> 6;      // wave = j-quarter
  const int l    = t & 63;
  const int col  = l & 15;
  const int ks   = l >> 4;

  __shared__ float s_dst[Nn];
  __shared__ float s_red[4];
  __shared__ float s_comb[3][64][9];
  __shared__ float s_ps[16];

  const float* dp = dst + b * Nn;
  float lm = -1e30f;
  for (int j = t; j < Nn; j += 256) { float v = dp[j]; s_dst[j] = v; lm = fmaxf(lm, v); }
#pragma unroll
  for (int mask = 32; mask >= 1; mask >>= 1) lm = fmaxf(lm, __shfl_xor(lm, mask));
  if (l == 0) s_red[jq] = lm;
  __syncthreads();
  const float dmax = fmaxf(fmaxf(s_red[0], s_red[1]), fmaxf(s_red[2], s_red[3]));

  const int i0 = tile * 16;
  const float si = src[b * Nn + i0 + col];
  const float t0v = si + dmax;
  const float em  = fmaxf(t0v, ALPHA * t0v) * LOG2E;

  auto pexp = [&](float dv) {
    const float tt = si + dv;
    const float u  = fmaxf(tt, ALPHA * tt);
    return exp2f(fmaf(u, LOG2E, -em));
  };

  const half8* bph = reinterpret_cast<const half8*>(hpT_hi + (size_t)b * F2n * Nn);
  const half8* bpl = reinterpret_cast<const half8*>(hpT_lo + (size_t)b * F2n * Nn);
  f32x4 acc0 = {0.f, 0.f, 0.f, 0.f};
  f32x4 acc1 = {0.f, 0.f, 0.f, 0.f};
  float psum = 0.f;

#pragma unroll 2
  for (int kb = 0; kb < 8; ++kb) {
    const int jb = jq * 8 + kb;
    const int jo = (jb << 5) | (ks << 3);
    const float4 dA = *reinterpret_cast<const float4*>(&s_dst[jo]);
    const float4 dB = *reinterpret_cast<const float4*>(&s_dst[jo + 4]);
    half8 af;
    const _Float16 q0 = (_Float16)pexp(dA.x); af[0] = q0;
    const _Float16 q1 = (_Float16)pexp(dA.y); af[1] = q1;
    const _Float16 q2 = (_Float16)pexp(dA.z); af[2] = q2;
    const _Float16 q3 = (_Float16)pexp(dA.w); af[3] = q3;
    const _Float16 q4 = (_Float16)pexp(dB.x); af[4] = q4;
    const _Float16 q5 = (_Float16)pexp(dB.y); af[5] = q5;
    const _Float16 q6 = (_Float16)pexp(dB.z); af[6] = q6;
    const _Float16 q7 = (_Float16)pexp(dB.w); af[7] = q7;
    psum += (((float)q0 + (float)q1) + ((float)q2 + (float)q3)) +
            (((float)q4 + (float)q5) + ((float)q6 + (float)q7));

    const half8 bh0 = bph[col * 128 + (jb << 2) + ks];
    const half8 bl0 = bpl[col * 128 + (jb << 2) + ks];
    const half8 bh1 = bph[(col + 16) * 128 + (jb << 2) + ks];
    const half8 bl1 = bpl[(col + 16) * 128 + (jb << 2) + ks];
    acc0 = __builtin_amdgcn_mfma_f32_16x16x32_f16(af, bh0, acc0, 0, 0, 0);
    acc0 = __builtin_amdgcn_mfma_f32_16x16x32_f16(af, bl0, acc0, 0, 0, 0);
    acc1 = __builtin_amdgcn_mfma_f32_16x16x32_f16(af, bh1, acc1, 0, 0, 0);
    acc1 = __builtin_amdgcn_mfma_f32_16x16x32_f16(af, bl1, acc1, 0, 0, 0);
  }

  if (jq > 0) {
#pragma unroll
    for (int r = 0; r < 4; ++r) {
      s_comb[jq - 1][l][r]     = acc0[r];
      s_comb[jq - 1][l][r + 4] = acc1[r];
    }
    s_comb[jq - 1][l][8] = psum;
  }
  __syncthreads();

  if (jq == 0) {
#pragma unroll
    for (int g = 0; g < 3; ++g) {
#pragma unroll
      for (int r = 0; r < 4; ++r) {
        acc0[r] += s_comb[g][l][r];
        acc1[r] += s_comb[g][l][r + 4];
      }
      psum += s_comb[g][l][8];
    }
    psum += __shfl_xor(psum, 16);
    psum += __shfl_xor(psum, 32);
    if (l < 16) s_ps[col] = psum;    // same-wave LDS: ordered

    const float bc0 = bias[col];
    const float bc1 = bias[col + 16];
#pragma unroll
    for (int r = 0; r < 4; ++r) {
      const int row = ks * 4 + r;
      const float inv = 1.f / s_ps[row];
      float* op = out + ((size_t)(b * Nn + i0 + row)) * F2n;
      op[col]      = fmaf(acc0[r], inv, bc0);
      op[col + 16] = fmaf(acc1[r], inv, bc1);
    }
  }
}

extern "C" void kernel_launch(void* const* d_in, const int* in_sizes, int n_in,
                              void* d_out, int out_size, void* d_ws, size_t ws_size,
                              hipStream_t stream) {
  (void)in_sizes; (void)n_in; (void)out_size; (void)ws_size;
  const float* x   = (const float*)d_in[0];
  const float* w1  = (const float*)d_in[1];
  const float* as1 = (const float*)d_in[2];
  const float* ad1 = (const float*)d_in[3];
  const float* b1  = (const float*)d_in[4];
  const float* w2  = (const float*)d_in[5];
  const float* as2 = (const float*)d_in[6];
  const float* ad2 = (const float*)d_in[7];
  const float* b2  = (const float*)d_in[8];
  float* out = (float*)d_out;

  float* ws = (float*)d_ws;
  short* hpT1_hi = (short*)ws;                         // 64*16*1024 sh = 524288 f
  short* hpT1_lo = (short*)(ws + 524288);              // 524288 f
  short* hpT2_hi = (short*)(ws + 1048576);             // 16*32*1024 sh = 262144 f
  short* hpT2_lo = (short*)(ws + 1048576 + 262144);    // 262144 f
  float* x1      = ws + 1048576 + 524288;              // 1048576 f
  float* src1    = x1 + 1048576;                       // 65536
  float* dst1    = src1 + 65536;                       // 65536
  float* src2    = dst1 + 65536;                       // 16384
  float* dst2    = src2 + 16384;                       // 16384
  float* statsA  = dst2 + 16384;                       // 16*128 = 2048

  k_proj1<<<256, 256, 0, stream>>>(x, w1, as1, ad1, hpT1_hi, hpT1_lo, src1, dst1, statsA);
  k_attn1<<<1024, 256, 0, stream>>>(hpT1_hi, hpT1_lo, src1, dst1, b1, x1, statsA);
  k_proj2<<<256, 256, 0, stream>>>(x1, statsA, w2, as2, ad2, hpT2_hi, hpT2_lo, src2, dst2);
  k_attn2<<<1024, 256, 0, stream>>>(hpT2_hi, hpT2_lo, src2, dst2, b2, out);
}